// Round 6
// baseline (460.512 us; speedup 1.0000x reference)
//
#include <hip/hip_runtime.h>
#include <math.h>

#define MAX_VEL 0.9f
#define REL_EPS 1e-6f

// Lorentz time-dilation weight from squared distance.
// w = sqrt(1 - (0.9*tanh(r))^2 + eps), tanh via fast exp: th = 1 - 2/(e^{2r}+1).
__device__ __forceinline__ float lorentz_w(float sq)
{
    float r = sqrtf(sq);
    float e = __expf(2.0f * r);
    float th = 1.0f - 2.0f / (e + 1.0f);
    return sqrtf(fmaf(-(MAX_VEL * MAX_VEL), th * th, 1.0f + REL_EPS));
}

// ---------------- CSR build: histogram of dst ----------------
__global__ void count_dst(const int* __restrict__ dst, int* __restrict__ cnt, int E)
{
    int e = blockIdx.x * blockDim.x + threadIdx.x;
    if (e < E) atomicAdd(&cnt[dst[e]], 1);
}

// ---------------- device-wide exclusive scan, 3 kernels ----------------
__global__ void scan_part1(const int* __restrict__ cnt, int* __restrict__ bsum, int N)
{
    int base = blockIdx.x * 1024 + threadIdx.x * 4;
    int s = 0;
    if (base + 3 < N) {
        int4 v = *reinterpret_cast<const int4*>(cnt + base);
        s = v.x + v.y + v.z + v.w;
    } else {
        for (int i = 0; i < 4; ++i) if (base + i < N) s += cnt[base + i];
    }
#pragma unroll
    for (int off = 32; off; off >>= 1) s += __shfl_xor(s, off);
    __shared__ int ws[4];
    if ((threadIdx.x & 63) == 0) ws[threadIdx.x >> 6] = s;
    __syncthreads();
    if (threadIdx.x == 0) bsum[blockIdx.x] = ws[0] + ws[1] + ws[2] + ws[3];
}

__global__ void scan_bsums(int* __restrict__ bsum, int NB)
{
    __shared__ int s[256];
    int t = threadIdx.x;
    int v = (t < NB) ? bsum[t] : 0;
    s[t] = v;
    __syncthreads();
    for (int off = 1; off < 256; off <<= 1) {
        int add = (t >= off) ? s[t - off] : 0;
        __syncthreads();
        s[t] += add;
        __syncthreads();
    }
    if (t < NB) bsum[t] = s[t] - v;   // exclusive
}

__global__ void scan_part2(const int* __restrict__ cnt, const int* __restrict__ bsum,
                           int* __restrict__ cursor, int N)
{
    int t = threadIdx.x;
    int base = blockIdx.x * 1024 + t * 4;
    int4 v = make_int4(0, 0, 0, 0);
    if (base + 3 < N) {
        v = *reinterpret_cast<const int4*>(cnt + base);
    } else if (base < N) {
        int* p = (int*)&v;
        for (int i = 0; i < 4; ++i) if (base + i < N) p[i] = cnt[base + i];
    }
    int tsum = v.x + v.y + v.z + v.w;
    int inc = tsum;
    int lane = t & 63;
#pragma unroll
    for (int off = 1; off < 64; off <<= 1) {
        int u = __shfl_up(inc, off);
        if (lane >= off) inc += u;
    }
    __shared__ int wtot[4];
    if (lane == 63) wtot[t >> 6] = inc;
    __syncthreads();
    int wid = t >> 6;
    int woff = 0;
    for (int i = 0; i < wid; ++i) woff += wtot[i];
    int excl = woff + (inc - tsum) + bsum[blockIdx.x];
    if (base < N) {
        int4 o;
        o.x = excl;
        o.y = excl + v.x;
        o.z = o.y + v.y;
        o.w = o.z + v.z;
        if (base + 3 < N) {
            *reinterpret_cast<int4*>(cursor + base) = o;
        } else {
            int* p = (int*)&o;
            for (int i = 0; i < 4; ++i) if (base + i < N) cursor[base + i] = p[i];
        }
    }
}

// ---------------- CSR scatter, XCD-partitioned by dst range ----------------
#define SC_EPB 1024
__global__ void scatter_edges_xcd(const int* __restrict__ src, const int* __restrict__ dst,
                                  int* __restrict__ cursor, int* __restrict__ src_sorted,
                                  int E, int N)
{
    int xcd = blockIdx.x & 7;
    int seg = blockIdx.x >> 3;
    int lo = (int)(((long long)N * xcd) >> 3);
    int hi = (int)(((long long)N * (xcd + 1)) >> 3);
    int base = seg * SC_EPB + threadIdx.x * 4;
    if (base >= E) return;
    int4 d4, s4;
    if (base + 3 < E) {
        d4 = *reinterpret_cast<const int4*>(dst + base);
        s4 = *reinterpret_cast<const int4*>(src + base);
    } else {
        int* dp = (int*)&d4; int* sp = (int*)&s4;
        for (int i = 0; i < 4; ++i) {
            dp[i] = (base + i < E) ? dst[base + i] : -1;
            sp[i] = (base + i < E) ? src[base + i] : 0;
        }
    }
    const int* dp = (const int*)&d4;
    const int* sp = (const int*)&s4;
#pragma unroll
    for (int i = 0; i < 4; ++i) {
        int d = dp[i];
        if (d >= lo && d < hi) {
            int p = atomicAdd(&cursor[d], 1);
            src_sorted[p] = sp[i];
        }
    }
}

// ---- generic weighted aggregate over CSR: agg[n] = sum_s w(s,n)*F[s], sumw[n] ----
// 16-lane group per node, float4 per lane, 2x unrolled with dual accumulators.
__global__ void agg_pass(const float* __restrict__ F, const int* __restrict__ cursor,
                         const int* __restrict__ cnt, const int* __restrict__ src_sorted,
                         float* __restrict__ agg, float* __restrict__ sumw, int N)
{
    int node = (blockIdx.x * blockDim.x + threadIdx.x) >> 4;
    int gl = threadIdx.x & 15;
    if (node >= N) return;
    int deg = cnt[node];
    int end = cursor[node];     // inclusive prefix after scatter
    int beg = end - deg;
    float4 fd = *reinterpret_cast<const float4*>(F + (size_t)node * 64 + gl * 4);
    float ax0 = 0.f, ay0 = 0.f, az0 = 0.f, aw0 = 0.f, sw0 = 0.f;
    float ax1 = 0.f, ay1 = 0.f, az1 = 0.f, aw1 = 0.f, sw1 = 0.f;
    int p = beg;
    for (; p + 2 <= end; p += 2) {
        int s0 = src_sorted[p];
        int s1 = src_sorted[p + 1];
        float4 f0 = *reinterpret_cast<const float4*>(F + (size_t)s0 * 64 + gl * 4);
        float4 f1 = *reinterpret_cast<const float4*>(F + (size_t)s1 * 64 + gl * 4);
        float dx0 = f0.x - fd.x, dy0 = f0.y - fd.y, dz0 = f0.z - fd.z, dw0 = f0.w - fd.w;
        float dx1 = f1.x - fd.x, dy1 = f1.y - fd.y, dz1 = f1.z - fd.z, dw1 = f1.w - fd.w;
        float sq0 = dx0 * dx0, sq1 = dx1 * dx1;
        sq0 = fmaf(dy0, dy0, sq0);  sq1 = fmaf(dy1, dy1, sq1);
        sq0 = fmaf(dz0, dz0, sq0);  sq1 = fmaf(dz1, dz1, sq1);
        sq0 = fmaf(dw0, dw0, sq0);  sq1 = fmaf(dw1, dw1, sq1);
        sq0 += __shfl_xor(sq0, 1);  sq1 += __shfl_xor(sq1, 1);
        sq0 += __shfl_xor(sq0, 2);  sq1 += __shfl_xor(sq1, 2);
        sq0 += __shfl_xor(sq0, 4);  sq1 += __shfl_xor(sq1, 4);
        sq0 += __shfl_xor(sq0, 8);  sq1 += __shfl_xor(sq1, 8);
        float w0 = lorentz_w(sq0);
        float w1 = lorentz_w(sq1);
        sw0 += w0;                  sw1 += w1;
        ax0 = fmaf(f0.x, w0, ax0);  ax1 = fmaf(f1.x, w1, ax1);
        ay0 = fmaf(f0.y, w0, ay0);  ay1 = fmaf(f1.y, w1, ay1);
        az0 = fmaf(f0.z, w0, az0);  az1 = fmaf(f1.z, w1, az1);
        aw0 = fmaf(f0.w, w0, aw0);  aw1 = fmaf(f1.w, w1, aw1);
    }
    if (p < end) {
        int s0 = src_sorted[p];
        float4 f0 = *reinterpret_cast<const float4*>(F + (size_t)s0 * 64 + gl * 4);
        float dx0 = f0.x - fd.x, dy0 = f0.y - fd.y, dz0 = f0.z - fd.z, dw0 = f0.w - fd.w;
        float sq0 = dx0 * dx0;
        sq0 = fmaf(dy0, dy0, sq0);
        sq0 = fmaf(dz0, dz0, sq0);
        sq0 = fmaf(dw0, dw0, sq0);
        sq0 += __shfl_xor(sq0, 1);
        sq0 += __shfl_xor(sq0, 2);
        sq0 += __shfl_xor(sq0, 4);
        sq0 += __shfl_xor(sq0, 8);
        float w0 = lorentz_w(sq0);
        sw0 += w0;
        ax0 = fmaf(f0.x, w0, ax0);
        ay0 = fmaf(f0.y, w0, ay0);
        az0 = fmaf(f0.z, w0, az0);
        aw0 = fmaf(f0.w, w0, aw0);
    }
    float4 o;
    o.x = ax0 + ax1;
    o.y = ay0 + ay1;
    o.z = az0 + az1;
    o.w = aw0 + aw1;
    *reinterpret_cast<float4*>(agg + (size_t)node * 64 + gl * 4) = o;
    if (gl == 0) sumw[node] = sw0 + sw1;
}

// ---- post-linear 1 (persistent): hidden = relu((aggx@W1 + b1*sumw)/max(deg,1)) ----
__global__ void lin1_post(const float* __restrict__ aggx, const float* __restrict__ W1,
                          const float* __restrict__ b1, const float* __restrict__ sumw,
                          const int* __restrict__ cnt, float* __restrict__ hidden, int N)
{
    __shared__ float sW[64 * 64];
    __shared__ float sB[64];
    for (int i = threadIdx.x; i < 64 * 64; i += blockDim.x) sW[i] = W1[i];
    if (threadIdx.x < 64) sB[threadIdx.x] = b1[threadIdx.x];
    __syncthreads();
    int c = threadIdx.x & 63;
    int sub = threadIdx.x >> 6;                 // 4 nodes per block-iteration
    for (int node = blockIdx.x * 4 + sub; node < N; node += gridDim.x * 4) {
        const float* ar = aggx + (size_t)node * 64;
        float acc = 0.0f;
#pragma unroll
        for (int k = 0; k < 64; k += 4) {
            float4 av = *reinterpret_cast<const float4*>(ar + k);
            acc = fmaf(av.x, sW[(k + 0) * 64 + c], acc);
            acc = fmaf(av.y, sW[(k + 1) * 64 + c], acc);
            acc = fmaf(av.z, sW[(k + 2) * 64 + c], acc);
            acc = fmaf(av.w, sW[(k + 3) * 64 + c], acc);
        }
        int dg = cnt[node];
        float inv = 1.0f / (dg > 1 ? (float)dg : 1.0f);
        float val = (acc + sB[c] * sumw[node]) * inv;
        hidden[(size_t)node * 64 + c] = fmaxf(val, 0.0f);
    }
}

// ---- post-linear 2 (persistent): out = (aggh@W2 + b2*sumw)/max(deg,1) ----
__global__ void lin2_post(const float* __restrict__ aggh, const float* __restrict__ W2,
                          const float* __restrict__ b2, const float* __restrict__ sumw,
                          const int* __restrict__ cnt, float* __restrict__ out, int N)
{
    __shared__ float sW[64 * 32];
    __shared__ float sB[32];
    for (int i = threadIdx.x; i < 64 * 32; i += blockDim.x) sW[i] = W2[i];
    if (threadIdx.x < 32) sB[threadIdx.x] = b2[threadIdx.x];
    __syncthreads();
    int c = threadIdx.x & 31;
    int sub = threadIdx.x >> 5;                 // 8 nodes per block-iteration
    for (int node = blockIdx.x * 8 + sub; node < N; node += gridDim.x * 8) {
        const float* ar = aggh + (size_t)node * 64;
        float acc = 0.0f;
#pragma unroll
        for (int k = 0; k < 64; k += 4) {
            float4 av = *reinterpret_cast<const float4*>(ar + k);
            acc = fmaf(av.x, sW[(k + 0) * 32 + c], acc);
            acc = fmaf(av.y, sW[(k + 1) * 32 + c], acc);
            acc = fmaf(av.z, sW[(k + 2) * 32 + c], acc);
            acc = fmaf(av.w, sW[(k + 3) * 32 + c], acc);
        }
        int dg = cnt[node];
        float inv = 1.0f / (dg > 1 ? (float)dg : 1.0f);
        out[(size_t)node * 32 + c] = (acc + sB[c] * sumw[node]) * inv;
    }
}

extern "C" void kernel_launch(void* const* d_in, const int* in_sizes, int n_in,
                              void* d_out, int out_size, void* d_ws, size_t ws_size,
                              hipStream_t stream)
{
    const float* x  = (const float*)d_in[0];
    const int*   ei = (const int*)d_in[1];
    const float* W1 = (const float*)d_in[2];
    const float* b1 = (const float*)d_in[3];
    const float* W2 = (const float*)d_in[4];
    const float* b2 = (const float*)d_in[5];
    float* out = (float*)d_out;

    const int N = in_sizes[0] / 64;
    const int E = in_sizes[1] / 2;
    const int* src = ei;
    const int* dst = ei + E;

    float* ws = (float*)d_ws;
    float* agg    = ws;                               // N*64 (aggx, then aggh)
    float* hidden = agg + (size_t)N * 64;             // N*64
    float* sumw   = hidden + (size_t)N * 64;          // N (layer1, then layer2)
    int*   cnt    = (int*)(sumw + N);                 // N
    int*   cursor = cnt + N;                          // N
    int*   bsum   = cursor + N;                       // <=256
    int*   src_sorted = bsum + 256;                   // E

    hipMemsetAsync(cnt, 0, (size_t)N * sizeof(int), stream);

    int eblk = (E + 255) / 256;
    count_dst<<<eblk, 256, 0, stream>>>(dst, cnt, E);

    int NB = (N + 1023) / 1024;                       // 98 for N=100k (<=256)
    scan_part1<<<NB, 256, 0, stream>>>(cnt, bsum, N);
    scan_bsums<<<1, 256, 0, stream>>>(bsum, NB);
    scan_part2<<<NB, 256, 0, stream>>>(cnt, bsum, cursor, N);

    int nseg = (E + SC_EPB - 1) / SC_EPB;
    scatter_edges_xcd<<<nseg * 8, 256, 0, stream>>>(src, dst, cursor, src_sorted, E, N);

    int gblk = (int)(((size_t)N * 16 + 255) / 256);   // 16 lanes per node
    agg_pass<<<gblk, 256, 0, stream>>>(x, cursor, cnt, src_sorted, agg, sumw, N);
    lin1_post<<<512, 256, 0, stream>>>(agg, W1, b1, sumw, cnt, hidden, N);

    agg_pass<<<gblk, 256, 0, stream>>>(hidden, cursor, cnt, src_sorted, agg, sumw, N);
    lin2_post<<<512, 256, 0, stream>>>(agg, W2, b2, sumw, cnt, out, N);
}

// Round 7
// 436.528 us; speedup vs baseline: 1.0549x; 1.0549x over previous
//
#include <hip/hip_runtime.h>
#include <math.h>

#define MAX_VEL 0.9f
#define REL_EPS 1e-6f

// Lorentz time-dilation weight from squared distance.
// w = sqrt(1 - (0.9*tanh(r))^2 + eps), tanh via fast exp: th = 1 - 2/(e^{2r}+1).
__device__ __forceinline__ float lorentz_w(float sq)
{
    float r = sqrtf(sq);
    float e = __expf(2.0f * r);
    float th = 1.0f - 2.0f / (e + 1.0f);
    return sqrtf(fmaf(-(MAX_VEL * MAX_VEL), th * th, 1.0f + REL_EPS));
}

// ---------------- CSR build: histogram of dst ----------------
__global__ void count_dst(const int* __restrict__ dst, int* __restrict__ cnt, int E)
{
    int e = blockIdx.x * blockDim.x + threadIdx.x;
    if (e < E) atomicAdd(&cnt[dst[e]], 1);
}

// ---------------- device-wide exclusive scan, 3 kernels ----------------
__global__ void scan_part1(const int* __restrict__ cnt, int* __restrict__ bsum, int N)
{
    int base = blockIdx.x * 1024 + threadIdx.x * 4;
    int s = 0;
    if (base + 3 < N) {
        int4 v = *reinterpret_cast<const int4*>(cnt + base);
        s = v.x + v.y + v.z + v.w;
    } else {
        for (int i = 0; i < 4; ++i) if (base + i < N) s += cnt[base + i];
    }
#pragma unroll
    for (int off = 32; off; off >>= 1) s += __shfl_xor(s, off);
    __shared__ int ws[4];
    if ((threadIdx.x & 63) == 0) ws[threadIdx.x >> 6] = s;
    __syncthreads();
    if (threadIdx.x == 0) bsum[blockIdx.x] = ws[0] + ws[1] + ws[2] + ws[3];
}

__global__ void scan_bsums(int* __restrict__ bsum, int NB)
{
    __shared__ int s[256];
    int t = threadIdx.x;
    int v = (t < NB) ? bsum[t] : 0;
    s[t] = v;
    __syncthreads();
    for (int off = 1; off < 256; off <<= 1) {
        int add = (t >= off) ? s[t - off] : 0;
        __syncthreads();
        s[t] += add;
        __syncthreads();
    }
    if (t < NB) bsum[t] = s[t] - v;   // exclusive
}

__global__ void scan_part2(const int* __restrict__ cnt, const int* __restrict__ bsum,
                           int* __restrict__ cursor, int N)
{
    int t = threadIdx.x;
    int base = blockIdx.x * 1024 + t * 4;
    int4 v = make_int4(0, 0, 0, 0);
    if (base + 3 < N) {
        v = *reinterpret_cast<const int4*>(cnt + base);
    } else if (base < N) {
        int* p = (int*)&v;
        for (int i = 0; i < 4; ++i) if (base + i < N) p[i] = cnt[base + i];
    }
    int tsum = v.x + v.y + v.z + v.w;
    int inc = tsum;
    int lane = t & 63;
#pragma unroll
    for (int off = 1; off < 64; off <<= 1) {
        int u = __shfl_up(inc, off);
        if (lane >= off) inc += u;
    }
    __shared__ int wtot[4];
    if (lane == 63) wtot[t >> 6] = inc;
    __syncthreads();
    int wid = t >> 6;
    int woff = 0;
    for (int i = 0; i < wid; ++i) woff += wtot[i];
    int excl = woff + (inc - tsum) + bsum[blockIdx.x];
    if (base < N) {
        int4 o;
        o.x = excl;
        o.y = excl + v.x;
        o.z = o.y + v.y;
        o.w = o.z + v.z;
        if (base + 3 < N) {
            *reinterpret_cast<int4*>(cursor + base) = o;
        } else {
            int* p = (int*)&o;
            for (int i = 0; i < 4; ++i) if (base + i < N) cursor[base + i] = p[i];
        }
    }
}

// ---------------- CSR scatter, XCD-partitioned by dst range ----------------
#define SC_EPB 1024
__global__ void scatter_edges_xcd(const int* __restrict__ src, const int* __restrict__ dst,
                                  int* __restrict__ cursor, int* __restrict__ src_sorted,
                                  int E, int N)
{
    int xcd = blockIdx.x & 7;
    int seg = blockIdx.x >> 3;
    int lo = (int)(((long long)N * xcd) >> 3);
    int hi = (int)(((long long)N * (xcd + 1)) >> 3);
    int base = seg * SC_EPB + threadIdx.x * 4;
    if (base >= E) return;
    int4 d4, s4;
    if (base + 3 < E) {
        d4 = *reinterpret_cast<const int4*>(dst + base);
        s4 = *reinterpret_cast<const int4*>(src + base);
    } else {
        int* dp = (int*)&d4; int* sp = (int*)&s4;
        for (int i = 0; i < 4; ++i) {
            dp[i] = (base + i < E) ? dst[base + i] : -1;
            sp[i] = (base + i < E) ? src[base + i] : 0;
        }
    }
    const int* dp = (const int*)&d4;
    const int* sp = (const int*)&s4;
#pragma unroll
    for (int i = 0; i < 4; ++i) {
        int d = dp[i];
        if (d >= lo && d < hi) {
            int p = atomicAdd(&cursor[d], 1);
            src_sorted[p] = sp[i];
        }
    }
}

// ---- generic weighted aggregate over CSR: agg[n] = sum_s w(s,n)*F[s], sumw[n] ----
// 16-lane group per node, float4 per lane, 2x unrolled with dual accumulators.
__global__ void agg_pass(const float* __restrict__ F, const int* __restrict__ cursor,
                         const int* __restrict__ cnt, const int* __restrict__ src_sorted,
                         float* __restrict__ agg, float* __restrict__ sumw, int N)
{
    int node = (blockIdx.x * blockDim.x + threadIdx.x) >> 4;
    int gl = threadIdx.x & 15;
    if (node >= N) return;
    int deg = cnt[node];
    int end = cursor[node];     // inclusive prefix after scatter
    int beg = end - deg;
    float4 fd = *reinterpret_cast<const float4*>(F + (size_t)node * 64 + gl * 4);
    float ax0 = 0.f, ay0 = 0.f, az0 = 0.f, aw0 = 0.f, sw0 = 0.f;
    float ax1 = 0.f, ay1 = 0.f, az1 = 0.f, aw1 = 0.f, sw1 = 0.f;
    int p = beg;
    for (; p + 2 <= end; p += 2) {
        int s0 = src_sorted[p];
        int s1 = src_sorted[p + 1];
        float4 f0 = *reinterpret_cast<const float4*>(F + (size_t)s0 * 64 + gl * 4);
        float4 f1 = *reinterpret_cast<const float4*>(F + (size_t)s1 * 64 + gl * 4);
        float dx0 = f0.x - fd.x, dy0 = f0.y - fd.y, dz0 = f0.z - fd.z, dw0 = f0.w - fd.w;
        float dx1 = f1.x - fd.x, dy1 = f1.y - fd.y, dz1 = f1.z - fd.z, dw1 = f1.w - fd.w;
        float sq0 = dx0 * dx0, sq1 = dx1 * dx1;
        sq0 = fmaf(dy0, dy0, sq0);  sq1 = fmaf(dy1, dy1, sq1);
        sq0 = fmaf(dz0, dz0, sq0);  sq1 = fmaf(dz1, dz1, sq1);
        sq0 = fmaf(dw0, dw0, sq0);  sq1 = fmaf(dw1, dw1, sq1);
        sq0 += __shfl_xor(sq0, 1);  sq1 += __shfl_xor(sq1, 1);
        sq0 += __shfl_xor(sq0, 2);  sq1 += __shfl_xor(sq1, 2);
        sq0 += __shfl_xor(sq0, 4);  sq1 += __shfl_xor(sq1, 4);
        sq0 += __shfl_xor(sq0, 8);  sq1 += __shfl_xor(sq1, 8);
        float w0 = lorentz_w(sq0);
        float w1 = lorentz_w(sq1);
        sw0 += w0;                  sw1 += w1;
        ax0 = fmaf(f0.x, w0, ax0);  ax1 = fmaf(f1.x, w1, ax1);
        ay0 = fmaf(f0.y, w0, ay0);  ay1 = fmaf(f1.y, w1, ay1);
        az0 = fmaf(f0.z, w0, az0);  az1 = fmaf(f1.z, w1, az1);
        aw0 = fmaf(f0.w, w0, aw0);  aw1 = fmaf(f1.w, w1, aw1);
    }
    if (p < end) {
        int s0 = src_sorted[p];
        float4 f0 = *reinterpret_cast<const float4*>(F + (size_t)s0 * 64 + gl * 4);
        float dx0 = f0.x - fd.x, dy0 = f0.y - fd.y, dz0 = f0.z - fd.z, dw0 = f0.w - fd.w;
        float sq0 = dx0 * dx0;
        sq0 = fmaf(dy0, dy0, sq0);
        sq0 = fmaf(dz0, dz0, sq0);
        sq0 = fmaf(dw0, dw0, sq0);
        sq0 += __shfl_xor(sq0, 1);
        sq0 += __shfl_xor(sq0, 2);
        sq0 += __shfl_xor(sq0, 4);
        sq0 += __shfl_xor(sq0, 8);
        float w0 = lorentz_w(sq0);
        sw0 += w0;
        ax0 = fmaf(f0.x, w0, ax0);
        ay0 = fmaf(f0.y, w0, ay0);
        az0 = fmaf(f0.z, w0, az0);
        aw0 = fmaf(f0.w, w0, aw0);
    }
    float4 o;
    o.x = ax0 + ax1;
    o.y = ay0 + ay1;
    o.z = az0 + az1;
    o.w = aw0 + aw1;
    *reinterpret_cast<float4*>(agg + (size_t)node * 64 + gl * 4) = o;
    if (gl == 0) sumw[node] = sw0 + sw1;
}

// FMA block helper: 4 channels of the row register r##i against W column c.
#define LIN_FMA4(i, STRIDE)                                         \
    acc = fmaf(r##i.x, sWc[(4 * i + 0) * STRIDE], acc);             \
    acc = fmaf(r##i.y, sWc[(4 * i + 1) * STRIDE], acc);             \
    acc = fmaf(r##i.z, sWc[(4 * i + 2) * STRIDE], acc);             \
    acc = fmaf(r##i.w, sWc[(4 * i + 3) * STRIDE], acc);

// ---- post-linear 1 (persistent, reg-pipelined): hidden = relu((agg@W1+b1*sumw)/deg) ----
__global__ void lin1_post(const float* __restrict__ aggx, const float* __restrict__ W1,
                          const float* __restrict__ b1, const float* __restrict__ sumw,
                          const int* __restrict__ cnt, float* __restrict__ hidden, int N)
{
    __shared__ float sW[64 * 64];
    __shared__ float sB[64];
    for (int i = threadIdx.x; i < 64 * 64; i += blockDim.x) sW[i] = W1[i];
    if (threadIdx.x < 64) sB[threadIdx.x] = b1[threadIdx.x];
    __syncthreads();
    int c = threadIdx.x & 63;
    int sub = threadIdx.x >> 6;                 // 4 nodes per block-iteration
    const float* sWc = sW + c;
    for (int node = blockIdx.x * 4 + sub; node < N; node += gridDim.x * 4) {
        const float4* ar = reinterpret_cast<const float4*>(aggx + (size_t)node * 64);
        // issue all 16 row loads + scalars before any use -> one L2 round-trip
        float4 r0 = ar[0], r1 = ar[1], r2 = ar[2], r3 = ar[3];
        float4 r4 = ar[4], r5 = ar[5], r6 = ar[6], r7 = ar[7];
        float4 r8 = ar[8], r9 = ar[9], r10 = ar[10], r11 = ar[11];
        float4 r12 = ar[12], r13 = ar[13], r14 = ar[14], r15 = ar[15];
        int dg = cnt[node];
        float sw = sumw[node];
        float acc = 0.0f;
        LIN_FMA4(0, 64)  LIN_FMA4(1, 64)  LIN_FMA4(2, 64)  LIN_FMA4(3, 64)
        LIN_FMA4(4, 64)  LIN_FMA4(5, 64)  LIN_FMA4(6, 64)  LIN_FMA4(7, 64)
        LIN_FMA4(8, 64)  LIN_FMA4(9, 64)  LIN_FMA4(10, 64) LIN_FMA4(11, 64)
        LIN_FMA4(12, 64) LIN_FMA4(13, 64) LIN_FMA4(14, 64) LIN_FMA4(15, 64)
        float inv = 1.0f / (dg > 1 ? (float)dg : 1.0f);
        float val = (acc + sB[c] * sw) * inv;
        hidden[(size_t)node * 64 + c] = fmaxf(val, 0.0f);
    }
}

// ---- post-linear 2 (persistent, reg-pipelined): out = (agg@W2+b2*sumw)/deg ----
__global__ void lin2_post(const float* __restrict__ aggh, const float* __restrict__ W2,
                          const float* __restrict__ b2, const float* __restrict__ sumw,
                          const int* __restrict__ cnt, float* __restrict__ out, int N)
{
    __shared__ float sW[64 * 32];
    __shared__ float sB[32];
    for (int i = threadIdx.x; i < 64 * 32; i += blockDim.x) sW[i] = W2[i];
    if (threadIdx.x < 32) sB[threadIdx.x] = b2[threadIdx.x];
    __syncthreads();
    int c = threadIdx.x & 31;
    int sub = threadIdx.x >> 5;                 // 8 nodes per block-iteration
    const float* sWc = sW + c;
    for (int node = blockIdx.x * 8 + sub; node < N; node += gridDim.x * 8) {
        const float4* ar = reinterpret_cast<const float4*>(aggh + (size_t)node * 64);
        float4 r0 = ar[0], r1 = ar[1], r2 = ar[2], r3 = ar[3];
        float4 r4 = ar[4], r5 = ar[5], r6 = ar[6], r7 = ar[7];
        float4 r8 = ar[8], r9 = ar[9], r10 = ar[10], r11 = ar[11];
        float4 r12 = ar[12], r13 = ar[13], r14 = ar[14], r15 = ar[15];
        int dg = cnt[node];
        float sw = sumw[node];
        float acc = 0.0f;
        LIN_FMA4(0, 32)  LIN_FMA4(1, 32)  LIN_FMA4(2, 32)  LIN_FMA4(3, 32)
        LIN_FMA4(4, 32)  LIN_FMA4(5, 32)  LIN_FMA4(6, 32)  LIN_FMA4(7, 32)
        LIN_FMA4(8, 32)  LIN_FMA4(9, 32)  LIN_FMA4(10, 32) LIN_FMA4(11, 32)
        LIN_FMA4(12, 32) LIN_FMA4(13, 32) LIN_FMA4(14, 32) LIN_FMA4(15, 32)
        float inv = 1.0f / (dg > 1 ? (float)dg : 1.0f);
        out[(size_t)node * 32 + c] = (acc + sB[c] * sw) * inv;
    }
}

extern "C" void kernel_launch(void* const* d_in, const int* in_sizes, int n_in,
                              void* d_out, int out_size, void* d_ws, size_t ws_size,
                              hipStream_t stream)
{
    const float* x  = (const float*)d_in[0];
    const int*   ei = (const int*)d_in[1];
    const float* W1 = (const float*)d_in[2];
    const float* b1 = (const float*)d_in[3];
    const float* W2 = (const float*)d_in[4];
    const float* b2 = (const float*)d_in[5];
    float* out = (float*)d_out;

    const int N = in_sizes[0] / 64;
    const int E = in_sizes[1] / 2;
    const int* src = ei;
    const int* dst = ei + E;

    float* ws = (float*)d_ws;
    float* agg    = ws;                               // N*64 (aggx, then aggh)
    float* hidden = agg + (size_t)N * 64;             // N*64
    float* sumw   = hidden + (size_t)N * 64;          // N (layer1, then layer2)
    int*   cnt    = (int*)(sumw + N);                 // N
    int*   cursor = cnt + N;                          // N
    int*   bsum   = cursor + N;                       // <=256
    int*   src_sorted = bsum + 256;                   // E

    hipMemsetAsync(cnt, 0, (size_t)N * sizeof(int), stream);

    int eblk = (E + 255) / 256;
    count_dst<<<eblk, 256, 0, stream>>>(dst, cnt, E);

    int NB = (N + 1023) / 1024;                       // 98 for N=100k (<=256)
    scan_part1<<<NB, 256, 0, stream>>>(cnt, bsum, N);
    scan_bsums<<<1, 256, 0, stream>>>(bsum, NB);
    scan_part2<<<NB, 256, 0, stream>>>(cnt, bsum, cursor, N);

    int nseg = (E + SC_EPB - 1) / SC_EPB;
    scatter_edges_xcd<<<nseg * 8, 256, 0, stream>>>(src, dst, cursor, src_sorted, E, N);

    int gblk = (int)(((size_t)N * 16 + 255) / 256);   // 16 lanes per node
    agg_pass<<<gblk, 256, 0, stream>>>(x, cursor, cnt, src_sorted, agg, sumw, N);
    lin1_post<<<2048, 256, 0, stream>>>(agg, W1, b1, sumw, cnt, hidden, N);

    agg_pass<<<gblk, 256, 0, stream>>>(hidden, cursor, cnt, src_sorted, agg, sumw, N);
    lin2_post<<<2048, 256, 0, stream>>>(agg, W2, b2, sumw, cnt, out, N);
}

// Round 8
// 378.246 us; speedup vs baseline: 1.2175x; 1.1541x over previous
//
#include <hip/hip_runtime.h>
#include <math.h>

#define MAX_VEL 0.9f
#define REL_EPS 1e-6f

// Lorentz time-dilation weight from squared distance.
// w = sqrt(1 - (0.9*tanh(r))^2 + eps), tanh via fast exp: th = 1 - 2/(e^{2r}+1).
__device__ __forceinline__ float lorentz_w(float sq)
{
    float r = sqrtf(sq);
    float e = __expf(2.0f * r);
    float th = 1.0f - 2.0f / (e + 1.0f);
    return sqrtf(fmaf(-(MAX_VEL * MAX_VEL), th * th, 1.0f + REL_EPS));
}

// ---------------- CSR build: histogram of dst ----------------
__global__ void count_dst(const int* __restrict__ dst, int* __restrict__ cnt, int E)
{
    int e = blockIdx.x * blockDim.x + threadIdx.x;
    if (e < E) atomicAdd(&cnt[dst[e]], 1);
}

// ---------------- device-wide exclusive scan, 3 kernels ----------------
__global__ void scan_part1(const int* __restrict__ cnt, int* __restrict__ bsum, int N)
{
    int base = blockIdx.x * 1024 + threadIdx.x * 4;
    int s = 0;
    if (base + 3 < N) {
        int4 v = *reinterpret_cast<const int4*>(cnt + base);
        s = v.x + v.y + v.z + v.w;
    } else {
        for (int i = 0; i < 4; ++i) if (base + i < N) s += cnt[base + i];
    }
#pragma unroll
    for (int off = 32; off; off >>= 1) s += __shfl_xor(s, off);
    __shared__ int ws[4];
    if ((threadIdx.x & 63) == 0) ws[threadIdx.x >> 6] = s;
    __syncthreads();
    if (threadIdx.x == 0) bsum[blockIdx.x] = ws[0] + ws[1] + ws[2] + ws[3];
}

__global__ void scan_bsums(int* __restrict__ bsum, int NB)
{
    __shared__ int s[256];
    int t = threadIdx.x;
    int v = (t < NB) ? bsum[t] : 0;
    s[t] = v;
    __syncthreads();
    for (int off = 1; off < 256; off <<= 1) {
        int add = (t >= off) ? s[t - off] : 0;
        __syncthreads();
        s[t] += add;
        __syncthreads();
    }
    if (t < NB) bsum[t] = s[t] - v;   // exclusive
}

__global__ void scan_part2(const int* __restrict__ cnt, const int* __restrict__ bsum,
                           int* __restrict__ cursor, int N)
{
    int t = threadIdx.x;
    int base = blockIdx.x * 1024 + t * 4;
    int4 v = make_int4(0, 0, 0, 0);
    if (base + 3 < N) {
        v = *reinterpret_cast<const int4*>(cnt + base);
    } else if (base < N) {
        int* p = (int*)&v;
        for (int i = 0; i < 4; ++i) if (base + i < N) p[i] = cnt[base + i];
    }
    int tsum = v.x + v.y + v.z + v.w;
    int inc = tsum;
    int lane = t & 63;
#pragma unroll
    for (int off = 1; off < 64; off <<= 1) {
        int u = __shfl_up(inc, off);
        if (lane >= off) inc += u;
    }
    __shared__ int wtot[4];
    if (lane == 63) wtot[t >> 6] = inc;
    __syncthreads();
    int wid = t >> 6;
    int woff = 0;
    for (int i = 0; i < wid; ++i) woff += wtot[i];
    int excl = woff + (inc - tsum) + bsum[blockIdx.x];
    if (base < N) {
        int4 o;
        o.x = excl;
        o.y = excl + v.x;
        o.z = o.y + v.y;
        o.w = o.z + v.z;
        if (base + 3 < N) {
            *reinterpret_cast<int4*>(cursor + base) = o;
        } else {
            int* p = (int*)&o;
            for (int i = 0; i < 4; ++i) if (base + i < N) cursor[base + i] = p[i];
        }
    }
}

// ---------------- CSR scatter, XCD-partitioned by dst range ----------------
#define SC_EPB 1024
__global__ void scatter_edges_xcd(const int* __restrict__ src, const int* __restrict__ dst,
                                  int* __restrict__ cursor, int* __restrict__ src_sorted,
                                  int E, int N)
{
    int xcd = blockIdx.x & 7;
    int seg = blockIdx.x >> 3;
    int lo = (int)(((long long)N * xcd) >> 3);
    int hi = (int)(((long long)N * (xcd + 1)) >> 3);
    int base = seg * SC_EPB + threadIdx.x * 4;
    if (base >= E) return;
    int4 d4, s4;
    if (base + 3 < E) {
        d4 = *reinterpret_cast<const int4*>(dst + base);
        s4 = *reinterpret_cast<const int4*>(src + base);
    } else {
        int* dp = (int*)&d4; int* sp = (int*)&s4;
        for (int i = 0; i < 4; ++i) {
            dp[i] = (base + i < E) ? dst[base + i] : -1;
            sp[i] = (base + i < E) ? src[base + i] : 0;
        }
    }
    const int* dp = (const int*)&d4;
    const int* sp = (const int*)&s4;
#pragma unroll
    for (int i = 0; i < 4; ++i) {
        int d = dp[i];
        if (d >= lo && d < hi) {
            int p = atomicAdd(&cursor[d], 1);
            src_sorted[p] = sp[i];
        }
    }
}

// ---- generic weighted aggregate over CSR: agg[n] = sum_s w(s,n)*F[s], sumw[n] ----
// 16-lane group per node, float4 per lane, 2x unrolled with dual accumulators.
__global__ void agg_pass(const float* __restrict__ F, const int* __restrict__ cursor,
                         const int* __restrict__ cnt, const int* __restrict__ src_sorted,
                         float* __restrict__ agg, float* __restrict__ sumw, int N)
{
    int node = (blockIdx.x * blockDim.x + threadIdx.x) >> 4;
    int gl = threadIdx.x & 15;
    if (node >= N) return;
    int deg = cnt[node];
    int end = cursor[node];     // inclusive prefix after scatter
    int beg = end - deg;
    float4 fd = *reinterpret_cast<const float4*>(F + (size_t)node * 64 + gl * 4);
    float ax0 = 0.f, ay0 = 0.f, az0 = 0.f, aw0 = 0.f, sw0 = 0.f;
    float ax1 = 0.f, ay1 = 0.f, az1 = 0.f, aw1 = 0.f, sw1 = 0.f;
    int p = beg;
    for (; p + 2 <= end; p += 2) {
        int s0 = src_sorted[p];
        int s1 = src_sorted[p + 1];
        float4 f0 = *reinterpret_cast<const float4*>(F + (size_t)s0 * 64 + gl * 4);
        float4 f1 = *reinterpret_cast<const float4*>(F + (size_t)s1 * 64 + gl * 4);
        float dx0 = f0.x - fd.x, dy0 = f0.y - fd.y, dz0 = f0.z - fd.z, dw0 = f0.w - fd.w;
        float dx1 = f1.x - fd.x, dy1 = f1.y - fd.y, dz1 = f1.z - fd.z, dw1 = f1.w - fd.w;
        float sq0 = dx0 * dx0, sq1 = dx1 * dx1;
        sq0 = fmaf(dy0, dy0, sq0);  sq1 = fmaf(dy1, dy1, sq1);
        sq0 = fmaf(dz0, dz0, sq0);  sq1 = fmaf(dz1, dz1, sq1);
        sq0 = fmaf(dw0, dw0, sq0);  sq1 = fmaf(dw1, dw1, sq1);
        sq0 += __shfl_xor(sq0, 1);  sq1 += __shfl_xor(sq1, 1);
        sq0 += __shfl_xor(sq0, 2);  sq1 += __shfl_xor(sq1, 2);
        sq0 += __shfl_xor(sq0, 4);  sq1 += __shfl_xor(sq1, 4);
        sq0 += __shfl_xor(sq0, 8);  sq1 += __shfl_xor(sq1, 8);
        float w0 = lorentz_w(sq0);
        float w1 = lorentz_w(sq1);
        sw0 += w0;                  sw1 += w1;
        ax0 = fmaf(f0.x, w0, ax0);  ax1 = fmaf(f1.x, w1, ax1);
        ay0 = fmaf(f0.y, w0, ay0);  ay1 = fmaf(f1.y, w1, ay1);
        az0 = fmaf(f0.z, w0, az0);  az1 = fmaf(f1.z, w1, az1);
        aw0 = fmaf(f0.w, w0, aw0);  aw1 = fmaf(f1.w, w1, aw1);
    }
    if (p < end) {
        int s0 = src_sorted[p];
        float4 f0 = *reinterpret_cast<const float4*>(F + (size_t)s0 * 64 + gl * 4);
        float dx0 = f0.x - fd.x, dy0 = f0.y - fd.y, dz0 = f0.z - fd.z, dw0 = f0.w - fd.w;
        float sq0 = dx0 * dx0;
        sq0 = fmaf(dy0, dy0, sq0);
        sq0 = fmaf(dz0, dz0, sq0);
        sq0 = fmaf(dw0, dw0, sq0);
        sq0 += __shfl_xor(sq0, 1);
        sq0 += __shfl_xor(sq0, 2);
        sq0 += __shfl_xor(sq0, 4);
        sq0 += __shfl_xor(sq0, 8);
        float w0 = lorentz_w(sq0);
        sw0 += w0;
        ax0 = fmaf(f0.x, w0, ax0);
        ay0 = fmaf(f0.y, w0, ay0);
        az0 = fmaf(f0.z, w0, az0);
        aw0 = fmaf(f0.w, w0, aw0);
    }
    float4 o;
    o.x = ax0 + ax1;
    o.y = ay0 + ay1;
    o.z = az0 + az1;
    o.w = aw0 + aw1;
    *reinterpret_cast<float4*>(agg + (size_t)node * 64 + gl * 4) = o;
    if (gl == 0) sumw[node] = sw0 + sw1;
}

// FMA block: row register r##i (4 channels) against W-column regs, 4 indep chains.
#define LIN_FMA4(i)                                   \
    a0 = fmaf(r##i.x, wreg[4 * i + 0], a0);           \
    a1 = fmaf(r##i.y, wreg[4 * i + 1], a1);           \
    a2 = fmaf(r##i.z, wreg[4 * i + 2], a2);           \
    a3 = fmaf(r##i.w, wreg[4 * i + 3], a3);

// ---- post-linear 1 (persistent, W column in VGPRs — no LDS in inner loop) ----
// hidden = relu((agg@W1 + b1*sumw) / max(deg,1))
__global__ __launch_bounds__(256) void lin1_post(
    const float* __restrict__ aggx, const float* __restrict__ W1,
    const float* __restrict__ b1, const float* __restrict__ sumw,
    const int* __restrict__ cnt, float* __restrict__ hidden, int N)
{
    int c = threadIdx.x & 63;
    float wreg[64];
#pragma unroll
    for (int k = 0; k < 64; ++k) wreg[k] = W1[k * 64 + c];   // column c, coalesced
    float bc = b1[c];
    int sub = threadIdx.x >> 6;                 // 4 nodes per block-iteration
    for (int node = blockIdx.x * 4 + sub; node < N; node += gridDim.x * 4) {
        const float4* ar = reinterpret_cast<const float4*>(aggx + (size_t)node * 64);
        float4 r0 = ar[0], r1 = ar[1], r2 = ar[2], r3 = ar[3];
        float4 r4 = ar[4], r5 = ar[5], r6 = ar[6], r7 = ar[7];
        float4 r8 = ar[8], r9 = ar[9], r10 = ar[10], r11 = ar[11];
        float4 r12 = ar[12], r13 = ar[13], r14 = ar[14], r15 = ar[15];
        int dg = cnt[node];
        float sw = sumw[node];
        float a0 = 0.f, a1 = 0.f, a2 = 0.f, a3 = 0.f;
        LIN_FMA4(0)  LIN_FMA4(1)  LIN_FMA4(2)  LIN_FMA4(3)
        LIN_FMA4(4)  LIN_FMA4(5)  LIN_FMA4(6)  LIN_FMA4(7)
        LIN_FMA4(8)  LIN_FMA4(9)  LIN_FMA4(10) LIN_FMA4(11)
        LIN_FMA4(12) LIN_FMA4(13) LIN_FMA4(14) LIN_FMA4(15)
        float acc = (a0 + a1) + (a2 + a3);
        float inv = 1.0f / (dg > 1 ? (float)dg : 1.0f);
        float val = (acc + bc * sw) * inv;
        hidden[(size_t)node * 64 + c] = fmaxf(val, 0.0f);
    }
}

// ---- post-linear 2 (persistent, W column in VGPRs): out = (agg@W2+b2*sumw)/deg ----
__global__ __launch_bounds__(256) void lin2_post(
    const float* __restrict__ aggh, const float* __restrict__ W2,
    const float* __restrict__ b2, const float* __restrict__ sumw,
    const int* __restrict__ cnt, float* __restrict__ out, int N)
{
    int c = threadIdx.x & 31;
    float wreg[64];
#pragma unroll
    for (int k = 0; k < 64; ++k) wreg[k] = W2[k * 32 + c];   // column c, coalesced
    float bc = b2[c];
    int sub = threadIdx.x >> 5;                 // 8 nodes per block-iteration
    for (int node = blockIdx.x * 8 + sub; node < N; node += gridDim.x * 8) {
        const float4* ar = reinterpret_cast<const float4*>(aggh + (size_t)node * 64);
        float4 r0 = ar[0], r1 = ar[1], r2 = ar[2], r3 = ar[3];
        float4 r4 = ar[4], r5 = ar[5], r6 = ar[6], r7 = ar[7];
        float4 r8 = ar[8], r9 = ar[9], r10 = ar[10], r11 = ar[11];
        float4 r12 = ar[12], r13 = ar[13], r14 = ar[14], r15 = ar[15];
        int dg = cnt[node];
        float sw = sumw[node];
        float a0 = 0.f, a1 = 0.f, a2 = 0.f, a3 = 0.f;
        LIN_FMA4(0)  LIN_FMA4(1)  LIN_FMA4(2)  LIN_FMA4(3)
        LIN_FMA4(4)  LIN_FMA4(5)  LIN_FMA4(6)  LIN_FMA4(7)
        LIN_FMA4(8)  LIN_FMA4(9)  LIN_FMA4(10) LIN_FMA4(11)
        LIN_FMA4(12) LIN_FMA4(13) LIN_FMA4(14) LIN_FMA4(15)
        float acc = (a0 + a1) + (a2 + a3);
        float inv = 1.0f / (dg > 1 ? (float)dg : 1.0f);
        out[(size_t)node * 32 + c] = (acc + bc * sw) * inv;
    }
}

extern "C" void kernel_launch(void* const* d_in, const int* in_sizes, int n_in,
                              void* d_out, int out_size, void* d_ws, size_t ws_size,
                              hipStream_t stream)
{
    const float* x  = (const float*)d_in[0];
    const int*   ei = (const int*)d_in[1];
    const float* W1 = (const float*)d_in[2];
    const float* b1 = (const float*)d_in[3];
    const float* W2 = (const float*)d_in[4];
    const float* b2 = (const float*)d_in[5];
    float* out = (float*)d_out;

    const int N = in_sizes[0] / 64;
    const int E = in_sizes[1] / 2;
    const int* src = ei;
    const int* dst = ei + E;

    float* ws = (float*)d_ws;
    float* agg    = ws;                               // N*64 (aggx, then aggh)
    float* hidden = agg + (size_t)N * 64;             // N*64
    float* sumw   = hidden + (size_t)N * 64;          // N (layer1, then layer2)
    int*   cnt    = (int*)(sumw + N);                 // N
    int*   cursor = cnt + N;                          // N
    int*   bsum   = cursor + N;                       // <=256
    int*   src_sorted = bsum + 256;                   // E

    hipMemsetAsync(cnt, 0, (size_t)N * sizeof(int), stream);

    int eblk = (E + 255) / 256;
    count_dst<<<eblk, 256, 0, stream>>>(dst, cnt, E);

    int NB = (N + 1023) / 1024;                       // 98 for N=100k (<=256)
    scan_part1<<<NB, 256, 0, stream>>>(cnt, bsum, N);
    scan_bsums<<<1, 256, 0, stream>>>(bsum, NB);
    scan_part2<<<NB, 256, 0, stream>>>(cnt, bsum, cursor, N);

    int nseg = (E + SC_EPB - 1) / SC_EPB;
    scatter_edges_xcd<<<nseg * 8, 256, 0, stream>>>(src, dst, cursor, src_sorted, E, N);

    int gblk = (int)(((size_t)N * 16 + 255) / 256);   // 16 lanes per node
    agg_pass<<<gblk, 256, 0, stream>>>(x, cursor, cnt, src_sorted, agg, sumw, N);
    lin1_post<<<2048, 256, 0, stream>>>(agg, W1, b1, sumw, cnt, hidden, N);

    agg_pass<<<gblk, 256, 0, stream>>>(hidden, cursor, cnt, src_sorted, agg, sumw, N);
    lin2_post<<<2048, 256, 0, stream>>>(agg, W2, b2, sumw, cnt, out, N);
}

// Round 9
// 362.420 us; speedup vs baseline: 1.2707x; 1.0437x over previous
//
#include <hip/hip_runtime.h>
#include <math.h>

#define MAX_VEL 0.9f
#define REL_EPS 1e-6f

// Fast Lorentz time-dilation weight from squared distance, native transcendentals.
// w = sqrt(1 - (0.9*tanh(r))^2 + eps),  tanh(r) = 1 - 2/(e^{2r}+1).
// v_sqrt/v_exp/v_rcp are ~1-2 ulp; tolerance budget is ~7x current error.
__device__ __forceinline__ float lorentz_w(float sq)
{
    float r  = __builtin_amdgcn_sqrtf(sq);
    float E  = __builtin_amdgcn_exp2f(r * 2.8853900817779268f);   // e^{2r} = 2^{2r*log2 e}
    float ip = __builtin_amdgcn_rcpf(E + 1.0f);
    float th = fmaf(-2.0f, ip, 1.0f);
    return __builtin_amdgcn_sqrtf(fmaf(-(MAX_VEL * MAX_VEL), th * th, 1.0f + REL_EPS));
}

// 16-lane group sum via DPP (single VALU add per step, no DS ops, stays in DPP row).
// steps: quad_perm[1,0,3,2] (xor1), quad_perm[2,3,0,1] (xor2),
//        row_half_mirror (pairs quads within 8), row_mirror (pairs 8s within 16).
__device__ __forceinline__ float group16_sum(float v)
{
    int t;
    t = __builtin_amdgcn_update_dpp(0, __float_as_int(v), 0xB1, 0xF, 0xF, true);
    v += __int_as_float(t);
    t = __builtin_amdgcn_update_dpp(0, __float_as_int(v), 0x4E, 0xF, 0xF, true);
    v += __int_as_float(t);
    t = __builtin_amdgcn_update_dpp(0, __float_as_int(v), 0x141, 0xF, 0xF, true);
    v += __int_as_float(t);
    t = __builtin_amdgcn_update_dpp(0, __float_as_int(v), 0x140, 0xF, 0xF, true);
    v += __int_as_float(t);
    return v;
}

// ---------------- CSR build: histogram of dst ----------------
__global__ void count_dst(const int* __restrict__ dst, int* __restrict__ cnt, int E)
{
    int e = blockIdx.x * blockDim.x + threadIdx.x;
    if (e < E) atomicAdd(&cnt[dst[e]], 1);
}

// ---------------- device-wide exclusive scan, 3 kernels ----------------
__global__ void scan_part1(const int* __restrict__ cnt, int* __restrict__ bsum, int N)
{
    int base = blockIdx.x * 1024 + threadIdx.x * 4;
    int s = 0;
    if (base + 3 < N) {
        int4 v = *reinterpret_cast<const int4*>(cnt + base);
        s = v.x + v.y + v.z + v.w;
    } else {
        for (int i = 0; i < 4; ++i) if (base + i < N) s += cnt[base + i];
    }
#pragma unroll
    for (int off = 32; off; off >>= 1) s += __shfl_xor(s, off);
    __shared__ int ws[4];
    if ((threadIdx.x & 63) == 0) ws[threadIdx.x >> 6] = s;
    __syncthreads();
    if (threadIdx.x == 0) bsum[blockIdx.x] = ws[0] + ws[1] + ws[2] + ws[3];
}

__global__ void scan_bsums(int* __restrict__ bsum, int NB)
{
    __shared__ int s[256];
    int t = threadIdx.x;
    int v = (t < NB) ? bsum[t] : 0;
    s[t] = v;
    __syncthreads();
    for (int off = 1; off < 256; off <<= 1) {
        int add = (t >= off) ? s[t - off] : 0;
        __syncthreads();
        s[t] += add;
        __syncthreads();
    }
    if (t < NB) bsum[t] = s[t] - v;   // exclusive
}

__global__ void scan_part2(const int* __restrict__ cnt, const int* __restrict__ bsum,
                           int* __restrict__ cursor, int N)
{
    int t = threadIdx.x;
    int base = blockIdx.x * 1024 + t * 4;
    int4 v = make_int4(0, 0, 0, 0);
    if (base + 3 < N) {
        v = *reinterpret_cast<const int4*>(cnt + base);
    } else if (base < N) {
        int* p = (int*)&v;
        for (int i = 0; i < 4; ++i) if (base + i < N) p[i] = cnt[base + i];
    }
    int tsum = v.x + v.y + v.z + v.w;
    int inc = tsum;
    int lane = t & 63;
#pragma unroll
    for (int off = 1; off < 64; off <<= 1) {
        int u = __shfl_up(inc, off);
        if (lane >= off) inc += u;
    }
    __shared__ int wtot[4];
    if (lane == 63) wtot[t >> 6] = inc;
    __syncthreads();
    int wid = t >> 6;
    int woff = 0;
    for (int i = 0; i < wid; ++i) woff += wtot[i];
    int excl = woff + (inc - tsum) + bsum[blockIdx.x];
    if (base < N) {
        int4 o;
        o.x = excl;
        o.y = excl + v.x;
        o.z = o.y + v.y;
        o.w = o.z + v.z;
        if (base + 3 < N) {
            *reinterpret_cast<int4*>(cursor + base) = o;
        } else {
            int* p = (int*)&o;
            for (int i = 0; i < 4; ++i) if (base + i < N) cursor[base + i] = p[i];
        }
    }
}

// ---------------- CSR scatter, XCD-partitioned by dst range ----------------
#define SC_EPB 1024
__global__ void scatter_edges_xcd(const int* __restrict__ src, const int* __restrict__ dst,
                                  int* __restrict__ cursor, int* __restrict__ src_sorted,
                                  int E, int N)
{
    int xcd = blockIdx.x & 7;
    int seg = blockIdx.x >> 3;
    int lo = (int)(((long long)N * xcd) >> 3);
    int hi = (int)(((long long)N * (xcd + 1)) >> 3);
    int base = seg * SC_EPB + threadIdx.x * 4;
    if (base >= E) return;
    int4 d4, s4;
    if (base + 3 < E) {
        d4 = *reinterpret_cast<const int4*>(dst + base);
        s4 = *reinterpret_cast<const int4*>(src + base);
    } else {
        int* dp = (int*)&d4; int* sp = (int*)&s4;
        for (int i = 0; i < 4; ++i) {
            dp[i] = (base + i < E) ? dst[base + i] : -1;
            sp[i] = (base + i < E) ? src[base + i] : 0;
        }
    }
    const int* dp = (const int*)&d4;
    const int* sp = (const int*)&s4;
#pragma unroll
    for (int i = 0; i < 4; ++i) {
        int d = dp[i];
        if (d >= lo && d < hi) {
            int p = atomicAdd(&cursor[d], 1);
            src_sorted[p] = sp[i];
        }
    }
}

// ---- generic weighted aggregate over CSR: agg[n] = sum_s w(s,n)*F[s], sumw[n] ----
// 16-lane group per node, float4 per lane, 2x unrolled, DPP group-sum, native math.
__global__ void agg_pass(const float* __restrict__ F, const int* __restrict__ cursor,
                         const int* __restrict__ cnt, const int* __restrict__ src_sorted,
                         float* __restrict__ agg, float* __restrict__ sumw, int N)
{
    int node = (blockIdx.x * blockDim.x + threadIdx.x) >> 4;
    int gl = threadIdx.x & 15;
    if (node >= N) return;
    int deg = cnt[node];
    int end = cursor[node];     // inclusive prefix after scatter
    int beg = end - deg;
    float4 fd = *reinterpret_cast<const float4*>(F + (size_t)node * 64 + gl * 4);
    float ax0 = 0.f, ay0 = 0.f, az0 = 0.f, aw0 = 0.f, sw0 = 0.f;
    float ax1 = 0.f, ay1 = 0.f, az1 = 0.f, aw1 = 0.f, sw1 = 0.f;
    int p = beg;
    for (; p + 2 <= end; p += 2) {
        int s0 = src_sorted[p];
        int s1 = src_sorted[p + 1];
        float4 f0 = *reinterpret_cast<const float4*>(F + (size_t)s0 * 64 + gl * 4);
        float4 f1 = *reinterpret_cast<const float4*>(F + (size_t)s1 * 64 + gl * 4);
        float dx0 = f0.x - fd.x, dy0 = f0.y - fd.y, dz0 = f0.z - fd.z, dw0 = f0.w - fd.w;
        float dx1 = f1.x - fd.x, dy1 = f1.y - fd.y, dz1 = f1.z - fd.z, dw1 = f1.w - fd.w;
        float sq0 = dx0 * dx0, sq1 = dx1 * dx1;
        sq0 = fmaf(dy0, dy0, sq0);  sq1 = fmaf(dy1, dy1, sq1);
        sq0 = fmaf(dz0, dz0, sq0);  sq1 = fmaf(dz1, dz1, sq1);
        sq0 = fmaf(dw0, dw0, sq0);  sq1 = fmaf(dw1, dw1, sq1);
        sq0 = group16_sum(sq0);
        sq1 = group16_sum(sq1);
        float w0 = lorentz_w(sq0);
        float w1 = lorentz_w(sq1);
        sw0 += w0;                  sw1 += w1;
        ax0 = fmaf(f0.x, w0, ax0);  ax1 = fmaf(f1.x, w1, ax1);
        ay0 = fmaf(f0.y, w0, ay0);  ay1 = fmaf(f1.y, w1, ay1);
        az0 = fmaf(f0.z, w0, az0);  az1 = fmaf(f1.z, w1, az1);
        aw0 = fmaf(f0.w, w0, aw0);  aw1 = fmaf(f1.w, w1, aw1);
    }
    if (p < end) {
        int s0 = src_sorted[p];
        float4 f0 = *reinterpret_cast<const float4*>(F + (size_t)s0 * 64 + gl * 4);
        float dx0 = f0.x - fd.x, dy0 = f0.y - fd.y, dz0 = f0.z - fd.z, dw0 = f0.w - fd.w;
        float sq0 = dx0 * dx0;
        sq0 = fmaf(dy0, dy0, sq0);
        sq0 = fmaf(dz0, dz0, sq0);
        sq0 = fmaf(dw0, dw0, sq0);
        sq0 = group16_sum(sq0);
        float w0 = lorentz_w(sq0);
        sw0 += w0;
        ax0 = fmaf(f0.x, w0, ax0);
        ay0 = fmaf(f0.y, w0, ay0);
        az0 = fmaf(f0.z, w0, az0);
        aw0 = fmaf(f0.w, w0, aw0);
    }
    float4 o;
    o.x = ax0 + ax1;
    o.y = ay0 + ay1;
    o.z = az0 + az1;
    o.w = aw0 + aw1;
    *reinterpret_cast<float4*>(agg + (size_t)node * 64 + gl * 4) = o;
    if (gl == 0) sumw[node] = sw0 + sw1;
}

// FMA block: row register r##i (4 channels) against W-column regs, 4 indep chains.
#define LIN_FMA4(i)                                   \
    a0 = fmaf(r##i.x, wreg[4 * i + 0], a0);           \
    a1 = fmaf(r##i.y, wreg[4 * i + 1], a1);           \
    a2 = fmaf(r##i.z, wreg[4 * i + 2], a2);           \
    a3 = fmaf(r##i.w, wreg[4 * i + 3], a3);

// ---- post-linear 1 (persistent, W column in VGPRs — no LDS in inner loop) ----
// hidden = relu((agg@W1 + b1*sumw) / max(deg,1))
__global__ __launch_bounds__(256) void lin1_post(
    const float* __restrict__ aggx, const float* __restrict__ W1,
    const float* __restrict__ b1, const float* __restrict__ sumw,
    const int* __restrict__ cnt, float* __restrict__ hidden, int N)
{
    int c = threadIdx.x & 63;
    float wreg[64];
#pragma unroll
    for (int k = 0; k < 64; ++k) wreg[k] = W1[k * 64 + c];   // column c, coalesced
    float bc = b1[c];
    int sub = threadIdx.x >> 6;                 // 4 nodes per block-iteration
    for (int node = blockIdx.x * 4 + sub; node < N; node += gridDim.x * 4) {
        const float4* ar = reinterpret_cast<const float4*>(aggx + (size_t)node * 64);
        float4 r0 = ar[0], r1 = ar[1], r2 = ar[2], r3 = ar[3];
        float4 r4 = ar[4], r5 = ar[5], r6 = ar[6], r7 = ar[7];
        float4 r8 = ar[8], r9 = ar[9], r10 = ar[10], r11 = ar[11];
        float4 r12 = ar[12], r13 = ar[13], r14 = ar[14], r15 = ar[15];
        int dg = cnt[node];
        float sw = sumw[node];
        float a0 = 0.f, a1 = 0.f, a2 = 0.f, a3 = 0.f;
        LIN_FMA4(0)  LIN_FMA4(1)  LIN_FMA4(2)  LIN_FMA4(3)
        LIN_FMA4(4)  LIN_FMA4(5)  LIN_FMA4(6)  LIN_FMA4(7)
        LIN_FMA4(8)  LIN_FMA4(9)  LIN_FMA4(10) LIN_FMA4(11)
        LIN_FMA4(12) LIN_FMA4(13) LIN_FMA4(14) LIN_FMA4(15)
        float acc = (a0 + a1) + (a2 + a3);
        float inv = 1.0f / (dg > 1 ? (float)dg : 1.0f);
        float val = (acc + bc * sw) * inv;
        hidden[(size_t)node * 64 + c] = fmaxf(val, 0.0f);
    }
}

// ---- post-linear 2 (persistent, W column in VGPRs): out = (agg@W2+b2*sumw)/deg ----
__global__ __launch_bounds__(256) void lin2_post(
    const float* __restrict__ aggh, const float* __restrict__ W2,
    const float* __restrict__ b2, const float* __restrict__ sumw,
    const int* __restrict__ cnt, float* __restrict__ out, int N)
{
    int c = threadIdx.x & 31;
    float wreg[64];
#pragma unroll
    for (int k = 0; k < 64; ++k) wreg[k] = W2[k * 32 + c];   // column c, coalesced
    float bc = b2[c];
    int sub = threadIdx.x >> 5;                 // 8 nodes per block-iteration
    for (int node = blockIdx.x * 8 + sub; node < N; node += gridDim.x * 8) {
        const float4* ar = reinterpret_cast<const float4*>(aggh + (size_t)node * 64);
        float4 r0 = ar[0], r1 = ar[1], r2 = ar[2], r3 = ar[3];
        float4 r4 = ar[4], r5 = ar[5], r6 = ar[6], r7 = ar[7];
        float4 r8 = ar[8], r9 = ar[9], r10 = ar[10], r11 = ar[11];
        float4 r12 = ar[12], r13 = ar[13], r14 = ar[14], r15 = ar[15];
        int dg = cnt[node];
        float sw = sumw[node];
        float a0 = 0.f, a1 = 0.f, a2 = 0.f, a3 = 0.f;
        LIN_FMA4(0)  LIN_FMA4(1)  LIN_FMA4(2)  LIN_FMA4(3)
        LIN_FMA4(4)  LIN_FMA4(5)  LIN_FMA4(6)  LIN_FMA4(7)
        LIN_FMA4(8)  LIN_FMA4(9)  LIN_FMA4(10) LIN_FMA4(11)
        LIN_FMA4(12) LIN_FMA4(13) LIN_FMA4(14) LIN_FMA4(15)
        float acc = (a0 + a1) + (a2 + a3);
        float inv = 1.0f / (dg > 1 ? (float)dg : 1.0f);
        out[(size_t)node * 32 + c] = (acc + bc * sw) * inv;
    }
}

extern "C" void kernel_launch(void* const* d_in, const int* in_sizes, int n_in,
                              void* d_out, int out_size, void* d_ws, size_t ws_size,
                              hipStream_t stream)
{
    const float* x  = (const float*)d_in[0];
    const int*   ei = (const int*)d_in[1];
    const float* W1 = (const float*)d_in[2];
    const float* b1 = (const float*)d_in[3];
    const float* W2 = (const float*)d_in[4];
    const float* b2 = (const float*)d_in[5];
    float* out = (float*)d_out;

    const int N = in_sizes[0] / 64;
    const int E = in_sizes[1] / 2;
    const int* src = ei;
    const int* dst = ei + E;

    float* ws = (float*)d_ws;
    float* agg    = ws;                               // N*64 (aggx, then aggh)
    float* hidden = agg + (size_t)N * 64;             // N*64
    float* sumw   = hidden + (size_t)N * 64;          // N (layer1, then layer2)
    int*   cnt    = (int*)(sumw + N);                 // N
    int*   cursor = cnt + N;                          // N
    int*   bsum   = cursor + N;                       // <=256
    int*   src_sorted = bsum + 256;                   // E

    hipMemsetAsync(cnt, 0, (size_t)N * sizeof(int), stream);

    int eblk = (E + 255) / 256;
    count_dst<<<eblk, 256, 0, stream>>>(dst, cnt, E);

    int NB = (N + 1023) / 1024;                       // 98 for N=100k (<=256)
    scan_part1<<<NB, 256, 0, stream>>>(cnt, bsum, N);
    scan_bsums<<<1, 256, 0, stream>>>(bsum, NB);
    scan_part2<<<NB, 256, 0, stream>>>(cnt, bsum, cursor, N);

    int nseg = (E + SC_EPB - 1) / SC_EPB;
    scatter_edges_xcd<<<nseg * 8, 256, 0, stream>>>(src, dst, cursor, src_sorted, E, N);

    int gblk = (int)(((size_t)N * 16 + 255) / 256);   // 16 lanes per node
    agg_pass<<<gblk, 256, 0, stream>>>(x, cursor, cnt, src_sorted, agg, sumw, N);
    lin1_post<<<2048, 256, 0, stream>>>(agg, W1, b1, sumw, cnt, hidden, N);

    agg_pass<<<gblk, 256, 0, stream>>>(hidden, cursor, cnt, src_sorted, agg, sumw, N);
    lin2_post<<<2048, 256, 0, stream>>>(agg, W2, b2, sumw, cnt, out, N);
}

// Round 11
// 361.807 us; speedup vs baseline: 1.2728x; 1.0017x over previous
//
#include <hip/hip_runtime.h>
#include <math.h>

#define MAX_VEL 0.9f
#define REL_EPS 1e-6f

typedef int v4i __attribute__((ext_vector_type(4)));   // clang vector for nt builtins

// Fast Lorentz time-dilation weight from squared distance, native transcendentals.
// w = sqrt(1 - (0.9*tanh(r))^2 + eps),  tanh(r) = 1 - 2/(e^{2r}+1).
__device__ __forceinline__ float lorentz_w(float sq)
{
    float r  = __builtin_amdgcn_sqrtf(sq);
    float E  = __builtin_amdgcn_exp2f(r * 2.8853900817779268f);   // e^{2r} = 2^{2r*log2 e}
    float ip = __builtin_amdgcn_rcpf(E + 1.0f);
    float th = fmaf(-2.0f, ip, 1.0f);
    return __builtin_amdgcn_sqrtf(fmaf(-(MAX_VEL * MAX_VEL), th * th, 1.0f + REL_EPS));
}

// 16-lane group sum via DPP (pure VALU, stays within the DPP row).
__device__ __forceinline__ float group16_sum(float v)
{
    int t;
    t = __builtin_amdgcn_update_dpp(0, __float_as_int(v), 0xB1, 0xF, 0xF, true);
    v += __int_as_float(t);
    t = __builtin_amdgcn_update_dpp(0, __float_as_int(v), 0x4E, 0xF, 0xF, true);
    v += __int_as_float(t);
    t = __builtin_amdgcn_update_dpp(0, __float_as_int(v), 0x141, 0xF, 0xF, true);
    v += __int_as_float(t);
    t = __builtin_amdgcn_update_dpp(0, __float_as_int(v), 0x140, 0xF, 0xF, true);
    v += __int_as_float(t);
    return v;
}

// ---------------- CSR build: histogram of dst (nt loads, 4 edges/thread) ----------------
__global__ void count_dst(const int* __restrict__ dst, int* __restrict__ cnt, int E)
{
    int base = (blockIdx.x * blockDim.x + threadIdx.x) * 4;
    if (base >= E) return;
    if (base + 3 < E) {
        v4i d = __builtin_nontemporal_load(reinterpret_cast<const v4i*>(dst + base));
        atomicAdd(&cnt[d.x], 1);
        atomicAdd(&cnt[d.y], 1);
        atomicAdd(&cnt[d.z], 1);
        atomicAdd(&cnt[d.w], 1);
    } else {
        for (int i = 0; i < 4 && base + i < E; ++i) atomicAdd(&cnt[dst[base + i]], 1);
    }
}

// ---------------- device-wide exclusive scan, 3 kernels ----------------
__global__ void scan_part1(const int* __restrict__ cnt, int* __restrict__ bsum, int N)
{
    int base = blockIdx.x * 1024 + threadIdx.x * 4;
    int s = 0;
    if (base + 3 < N) {
        int4 v = *reinterpret_cast<const int4*>(cnt + base);
        s = v.x + v.y + v.z + v.w;
    } else {
        for (int i = 0; i < 4; ++i) if (base + i < N) s += cnt[base + i];
    }
#pragma unroll
    for (int off = 32; off; off >>= 1) s += __shfl_xor(s, off);
    __shared__ int ws[4];
    if ((threadIdx.x & 63) == 0) ws[threadIdx.x >> 6] = s;
    __syncthreads();
    if (threadIdx.x == 0) bsum[blockIdx.x] = ws[0] + ws[1] + ws[2] + ws[3];
}

__global__ void scan_bsums(int* __restrict__ bsum, int NB)
{
    __shared__ int s[256];
    int t = threadIdx.x;
    int v = (t < NB) ? bsum[t] : 0;
    s[t] = v;
    __syncthreads();
    for (int off = 1; off < 256; off <<= 1) {
        int add = (t >= off) ? s[t - off] : 0;
        __syncthreads();
        s[t] += add;
        __syncthreads();
    }
    if (t < NB) bsum[t] = s[t] - v;   // exclusive
}

__global__ void scan_part2(const int* __restrict__ cnt, const int* __restrict__ bsum,
                           int* __restrict__ cursor, int N)
{
    int t = threadIdx.x;
    int base = blockIdx.x * 1024 + t * 4;
    int4 v = make_int4(0, 0, 0, 0);
    if (base + 3 < N) {
        v = *reinterpret_cast<const int4*>(cnt + base);
    } else if (base < N) {
        int* p = (int*)&v;
        for (int i = 0; i < 4; ++i) if (base + i < N) p[i] = cnt[base + i];
    }
    int tsum = v.x + v.y + v.z + v.w;
    int inc = tsum;
    int lane = t & 63;
#pragma unroll
    for (int off = 1; off < 64; off <<= 1) {
        int u = __shfl_up(inc, off);
        if (lane >= off) inc += u;
    }
    __shared__ int wtot[4];
    if (lane == 63) wtot[t >> 6] = inc;
    __syncthreads();
    int wid = t >> 6;
    int woff = 0;
    for (int i = 0; i < wid; ++i) woff += wtot[i];
    int excl = woff + (inc - tsum) + bsum[blockIdx.x];
    if (base < N) {
        int4 o;
        o.x = excl;
        o.y = excl + v.x;
        o.z = o.y + v.y;
        o.w = o.z + v.z;
        if (base + 3 < N) {
            *reinterpret_cast<int4*>(cursor + base) = o;
        } else {
            int* p = (int*)&o;
            for (int i = 0; i < 4; ++i) if (base + i < N) cursor[base + i] = p[i];
        }
    }
}

// ---------------- CSR scatter, XCD-partitioned, nt streaming reads ----------------
// nt loads keep the streaming src/dst scan out of L2 so the partially-written
// src_sorted lines stay resident and write-combine (kills the 12x write blowup).
#define SC_EPB 1024
__global__ void scatter_edges_xcd(const int* __restrict__ src, const int* __restrict__ dst,
                                  int* __restrict__ cursor, int* __restrict__ src_sorted,
                                  int E, int N)
{
    int xcd = blockIdx.x & 7;
    int seg = blockIdx.x >> 3;
    int lo = (int)(((long long)N * xcd) >> 3);
    int hi = (int)(((long long)N * (xcd + 1)) >> 3);
    int base = seg * SC_EPB + threadIdx.x * 4;
    if (base >= E) return;
    v4i d4, s4;
    if (base + 3 < E) {
        d4 = __builtin_nontemporal_load(reinterpret_cast<const v4i*>(dst + base));
        s4 = __builtin_nontemporal_load(reinterpret_cast<const v4i*>(src + base));
    } else {
        for (int i = 0; i < 4; ++i) {
            d4[i] = (base + i < E) ? dst[base + i] : -1;
            s4[i] = (base + i < E) ? src[base + i] : 0;
        }
    }
#pragma unroll
    for (int i = 0; i < 4; ++i) {
        int d = d4[i];
        if (d >= lo && d < hi) {
            int p = atomicAdd(&cursor[d], 1);
            src_sorted[p] = s4[i];
        }
    }
}

// ---- generic weighted aggregate over CSR: agg[n] = sum_s w(s,n)*F[s], sumw[n] ----
// 16-lane group per node, float4 per lane, 4x unrolled (4 gathers in flight).
__global__ void agg_pass(const float* __restrict__ F, const int* __restrict__ cursor,
                         const int* __restrict__ cnt, const int* __restrict__ src_sorted,
                         float* __restrict__ agg, float* __restrict__ sumw, int N)
{
    int node = (blockIdx.x * blockDim.x + threadIdx.x) >> 4;
    int gl = threadIdx.x & 15;
    if (node >= N) return;
    int deg = cnt[node];
    int end = cursor[node];     // inclusive prefix after scatter
    int beg = end - deg;
    float4 fd = *reinterpret_cast<const float4*>(F + (size_t)node * 64 + gl * 4);
    float ax0 = 0.f, ay0 = 0.f, az0 = 0.f, aw0 = 0.f, sw0 = 0.f;
    float ax1 = 0.f, ay1 = 0.f, az1 = 0.f, aw1 = 0.f, sw1 = 0.f;
    int p = beg;
    for (; p + 4 <= end; p += 4) {
        int s0 = src_sorted[p];
        int s1 = src_sorted[p + 1];
        int s2 = src_sorted[p + 2];
        int s3 = src_sorted[p + 3];
        // 4 independent row gathers issued back-to-back
        float4 f0 = *reinterpret_cast<const float4*>(F + (size_t)s0 * 64 + gl * 4);
        float4 f1 = *reinterpret_cast<const float4*>(F + (size_t)s1 * 64 + gl * 4);
        float4 f2 = *reinterpret_cast<const float4*>(F + (size_t)s2 * 64 + gl * 4);
        float4 f3 = *reinterpret_cast<const float4*>(F + (size_t)s3 * 64 + gl * 4);
        float sq0 = (f0.x - fd.x) * (f0.x - fd.x);
        float sq1 = (f1.x - fd.x) * (f1.x - fd.x);
        float sq2 = (f2.x - fd.x) * (f2.x - fd.x);
        float sq3 = (f3.x - fd.x) * (f3.x - fd.x);
        sq0 = fmaf(f0.y - fd.y, f0.y - fd.y, sq0);
        sq1 = fmaf(f1.y - fd.y, f1.y - fd.y, sq1);
        sq2 = fmaf(f2.y - fd.y, f2.y - fd.y, sq2);
        sq3 = fmaf(f3.y - fd.y, f3.y - fd.y, sq3);
        sq0 = fmaf(f0.z - fd.z, f0.z - fd.z, sq0);
        sq1 = fmaf(f1.z - fd.z, f1.z - fd.z, sq1);
        sq2 = fmaf(f2.z - fd.z, f2.z - fd.z, sq2);
        sq3 = fmaf(f3.z - fd.z, f3.z - fd.z, sq3);
        sq0 = fmaf(f0.w - fd.w, f0.w - fd.w, sq0);
        sq1 = fmaf(f1.w - fd.w, f1.w - fd.w, sq1);
        sq2 = fmaf(f2.w - fd.w, f2.w - fd.w, sq2);
        sq3 = fmaf(f3.w - fd.w, f3.w - fd.w, sq3);
        sq0 = group16_sum(sq0);
        sq1 = group16_sum(sq1);
        sq2 = group16_sum(sq2);
        sq3 = group16_sum(sq3);
        float w0 = lorentz_w(sq0);
        float w1 = lorentz_w(sq1);
        float w2 = lorentz_w(sq2);
        float w3 = lorentz_w(sq3);
        sw0 += w0 + w2;
        sw1 += w1 + w3;
        ax0 = fmaf(f0.x, w0, ax0);  ax1 = fmaf(f1.x, w1, ax1);
        ay0 = fmaf(f0.y, w0, ay0);  ay1 = fmaf(f1.y, w1, ay1);
        az0 = fmaf(f0.z, w0, az0);  az1 = fmaf(f1.z, w1, az1);
        aw0 = fmaf(f0.w, w0, aw0);  aw1 = fmaf(f1.w, w1, aw1);
        ax0 = fmaf(f2.x, w2, ax0);  ax1 = fmaf(f3.x, w3, ax1);
        ay0 = fmaf(f2.y, w2, ay0);  ay1 = fmaf(f3.y, w3, ay1);
        az0 = fmaf(f2.z, w2, az0);  az1 = fmaf(f3.z, w3, az1);
        aw0 = fmaf(f2.w, w2, aw0);  aw1 = fmaf(f3.w, w3, aw1);
    }
    for (; p < end; ++p) {
        int s0 = src_sorted[p];
        float4 f0 = *reinterpret_cast<const float4*>(F + (size_t)s0 * 64 + gl * 4);
        float dx = f0.x - fd.x, dy = f0.y - fd.y, dz = f0.z - fd.z, dw = f0.w - fd.w;
        float sq0 = dx * dx;
        sq0 = fmaf(dy, dy, sq0);
        sq0 = fmaf(dz, dz, sq0);
        sq0 = fmaf(dw, dw, sq0);
        sq0 = group16_sum(sq0);
        float w0 = lorentz_w(sq0);
        sw0 += w0;
        ax0 = fmaf(f0.x, w0, ax0);
        ay0 = fmaf(f0.y, w0, ay0);
        az0 = fmaf(f0.z, w0, az0);
        aw0 = fmaf(f0.w, w0, aw0);
    }
    float4 o;
    o.x = ax0 + ax1;
    o.y = ay0 + ay1;
    o.z = az0 + az1;
    o.w = aw0 + aw1;
    *reinterpret_cast<float4*>(agg + (size_t)node * 64 + gl * 4) = o;
    if (gl == 0) sumw[node] = sw0 + sw1;
}

// FMA block: row register r##i (4 channels) against W-column regs, 4 indep chains.
#define LIN_FMA4(i)                                   \
    a0 = fmaf(r##i.x, wreg[4 * i + 0], a0);           \
    a1 = fmaf(r##i.y, wreg[4 * i + 1], a1);           \
    a2 = fmaf(r##i.z, wreg[4 * i + 2], a2);           \
    a3 = fmaf(r##i.w, wreg[4 * i + 3], a3);

// ---- post-linear 1 (persistent, W column in VGPRs — no LDS in inner loop) ----
__global__ __launch_bounds__(256) void lin1_post(
    const float* __restrict__ aggx, const float* __restrict__ W1,
    const float* __restrict__ b1, const float* __restrict__ sumw,
    const int* __restrict__ cnt, float* __restrict__ hidden, int N)
{
    int c = threadIdx.x & 63;
    float wreg[64];
#pragma unroll
    for (int k = 0; k < 64; ++k) wreg[k] = W1[k * 64 + c];   // column c, coalesced
    float bc = b1[c];
    int sub = threadIdx.x >> 6;                 // 4 nodes per block-iteration
    for (int node = blockIdx.x * 4 + sub; node < N; node += gridDim.x * 4) {
        const float4* ar = reinterpret_cast<const float4*>(aggx + (size_t)node * 64);
        float4 r0 = ar[0], r1 = ar[1], r2 = ar[2], r3 = ar[3];
        float4 r4 = ar[4], r5 = ar[5], r6 = ar[6], r7 = ar[7];
        float4 r8 = ar[8], r9 = ar[9], r10 = ar[10], r11 = ar[11];
        float4 r12 = ar[12], r13 = ar[13], r14 = ar[14], r15 = ar[15];
        int dg = cnt[node];
        float sw = sumw[node];
        float a0 = 0.f, a1 = 0.f, a2 = 0.f, a3 = 0.f;
        LIN_FMA4(0)  LIN_FMA4(1)  LIN_FMA4(2)  LIN_FMA4(3)
        LIN_FMA4(4)  LIN_FMA4(5)  LIN_FMA4(6)  LIN_FMA4(7)
        LIN_FMA4(8)  LIN_FMA4(9)  LIN_FMA4(10) LIN_FMA4(11)
        LIN_FMA4(12) LIN_FMA4(13) LIN_FMA4(14) LIN_FMA4(15)
        float acc = (a0 + a1) + (a2 + a3);
        float inv = 1.0f / (dg > 1 ? (float)dg : 1.0f);
        float val = (acc + bc * sw) * inv;
        hidden[(size_t)node * 64 + c] = fmaxf(val, 0.0f);
    }
}

// ---- post-linear 2 (persistent, W column in VGPRs): out = (agg@W2+b2*sumw)/deg ----
__global__ __launch_bounds__(256) void lin2_post(
    const float* __restrict__ aggh, const float* __restrict__ W2,
    const float* __restrict__ b2, const float* __restrict__ sumw,
    const int* __restrict__ cnt, float* __restrict__ out, int N)
{
    int c = threadIdx.x & 31;
    float wreg[64];
#pragma unroll
    for (int k = 0; k < 64; ++k) wreg[k] = W2[k * 32 + c];   // column c, coalesced
    float bc = b2[c];
    int sub = threadIdx.x >> 5;                 // 8 nodes per block-iteration
    for (int node = blockIdx.x * 8 + sub; node < N; node += gridDim.x * 8) {
        const float4* ar = reinterpret_cast<const float4*>(aggh + (size_t)node * 64);
        float4 r0 = ar[0], r1 = ar[1], r2 = ar[2], r3 = ar[3];
        float4 r4 = ar[4], r5 = ar[5], r6 = ar[6], r7 = ar[7];
        float4 r8 = ar[8], r9 = ar[9], r10 = ar[10], r11 = ar[11];
        float4 r12 = ar[12], r13 = ar[13], r14 = ar[14], r15 = ar[15];
        int dg = cnt[node];
        float sw = sumw[node];
        float a0 = 0.f, a1 = 0.f, a2 = 0.f, a3 = 0.f;
        LIN_FMA4(0)  LIN_FMA4(1)  LIN_FMA4(2)  LIN_FMA4(3)
        LIN_FMA4(4)  LIN_FMA4(5)  LIN_FMA4(6)  LIN_FMA4(7)
        LIN_FMA4(8)  LIN_FMA4(9)  LIN_FMA4(10) LIN_FMA4(11)
        LIN_FMA4(12) LIN_FMA4(13) LIN_FMA4(14) LIN_FMA4(15)
        float acc = (a0 + a1) + (a2 + a3);
        float inv = 1.0f / (dg > 1 ? (float)dg : 1.0f);
        out[(size_t)node * 32 + c] = (acc + bc * sw) * inv;
    }
}

extern "C" void kernel_launch(void* const* d_in, const int* in_sizes, int n_in,
                              void* d_out, int out_size, void* d_ws, size_t ws_size,
                              hipStream_t stream)
{
    const float* x  = (const float*)d_in[0];
    const int*   ei = (const int*)d_in[1];
    const float* W1 = (const float*)d_in[2];
    const float* b1 = (const float*)d_in[3];
    const float* W2 = (const float*)d_in[4];
    const float* b2 = (const float*)d_in[5];
    float* out = (float*)d_out;

    const int N = in_sizes[0] / 64;
    const int E = in_sizes[1] / 2;
    const int* src = ei;
    const int* dst = ei + E;

    float* ws = (float*)d_ws;
    float* agg    = ws;                               // N*64 (aggx, then aggh)
    float* hidden = agg + (size_t)N * 64;             // N*64
    float* sumw   = hidden + (size_t)N * 64;          // N (layer1, then layer2)
    int*   cnt    = (int*)(sumw + N);                 // N
    int*   cursor = cnt + N;                          // N
    int*   bsum   = cursor + N;                       // <=256
    int*   src_sorted = bsum + 256;                   // E

    (void)hipMemsetAsync(cnt, 0, (size_t)N * sizeof(int), stream);

    int cblk = (E / 4 + 255) / 256;
    count_dst<<<cblk, 256, 0, stream>>>(dst, cnt, E);

    int NB = (N + 1023) / 1024;                       // 98 for N=100k (<=256)
    scan_part1<<<NB, 256, 0, stream>>>(cnt, bsum, N);
    scan_bsums<<<1, 256, 0, stream>>>(bsum, NB);
    scan_part2<<<NB, 256, 0, stream>>>(cnt, bsum, cursor, N);

    int nseg = (E + SC_EPB - 1) / SC_EPB;
    scatter_edges_xcd<<<nseg * 8, 256, 0, stream>>>(src, dst, cursor, src_sorted, E, N);

    int gblk = (int)(((size_t)N * 16 + 255) / 256);   // 16 lanes per node
    agg_pass<<<gblk, 256, 0, stream>>>(x, cursor, cnt, src_sorted, agg, sumw, N);
    lin1_post<<<2048, 256, 0, stream>>>(agg, W1, b1, sumw, cnt, hidden, N);

    agg_pass<<<gblk, 256, 0, stream>>>(hidden, cursor, cnt, src_sorted, agg, sumw, N);
    lin2_post<<<2048, 256, 0, stream>>>(agg, W2, b2, sumw, cnt, out, N);
}